// Round 1
// baseline (607.981 us; speedup 1.0000x reference)
//
#include <hip/hip_runtime.h>
#include <hip/hip_bf16.h>

// Problem constants (B=2, S=1024, E=512, H=2048, P=128, W=257)
#define S_LEN 1024
#define E_DIM 512
#define H_DIM 2048
#define P_PAD 128
#define W_WIN 257
#define EXT_LEN (S_LEN + 2 * P_PAD)   // 1280
#define BS_ROWS (2 * S_LEN)           // 2048

// ---------------- reductions ----------------
__device__ inline float wave_reduce_sum(float v) {
#pragma unroll
  for (int off = 32; off >= 1; off >>= 1) v += __shfl_xor(v, off);
  return v;
}
__device__ inline float wave_reduce_max(float v) {
#pragma unroll
  for (int off = 32; off >= 1; off >>= 1) v = fmaxf(v, __shfl_xor(v, off));
  return v;
}

// ---------------- PE add ----------------
__global__ __launch_bounds__(256) void pe_add_kernel(const float* __restrict__ x,
                                                     float* __restrict__ xpe) {
  int idx = blockIdx.x * 256 + threadIdx.x;  // exactly 2*1024*512 threads
  int e = idx & (E_DIM - 1);
  int s = (idx >> 9) & (S_LEN - 1);
  const float c = -9.210340371976184f / 512.0f;  // -ln(10000)/E
  float freq = expf((float)(e & ~1) * c);
  float ang = (float)s * freq;
  float pe = (e & 1) ? cosf(ang) : sinf(ang);
  xpe[idx] = x[idx] + pe;
}

// ---------------- pad fill for k_ext / v_ext ----------------
__global__ __launch_bounds__(256) void fill_pads_kernel(const float* __restrict__ bk,
                                                        const float* __restrict__ bv,
                                                        float* __restrict__ k_ext,
                                                        float* __restrict__ v_ext) {
  int idx = blockIdx.x * 256 + threadIdx.x;  // 2 tensors * 2 batch * 256 rows * 512
  int e = idx & (E_DIM - 1);
  int rr = (idx >> 9) & 255;   // pad row 0..255
  int b = (idx >> 17) & 1;
  int t = idx >> 18;
  int ext_row = (rr < P_PAD) ? rr : (S_LEN + rr);  // front pad or back pad
  float* dst = t ? v_ext : k_ext;
  const float* src = t ? bv : bk;
  dst[((size_t)(b * EXT_LEN + ext_row)) * E_DIM + e] = src[e];
}

// ---------------- tiled fp32 GEMM: C = A(MxK) @ B(KxN) + bias, opt relu ----------------
// BM=128, BN=64, BK=16. 256 threads (16x16), each 8x4 microtile.
template <bool RELU, bool KV>
__global__ __launch_bounds__(256) void gemm_kernel(const float* __restrict__ A,
                                                   const float* __restrict__ B,
                                                   const float* __restrict__ bias,
                                                   float* __restrict__ C,
                                                   int M, int N, int K) {
  __shared__ float As[16][132];  // transposed: As[k][m]; 132 keeps 16B align + bank spread
  __shared__ float Bs[16][68];
  const int tid = threadIdx.x;
  const int tx = tid & 15;
  const int ty = tid >> 4;
  const int col0 = blockIdx.x * 64;
  const int row0 = blockIdx.y * 128;
  float acc[8][4] = {};

  for (int k0 = 0; k0 < K; k0 += 16) {
    // A tile: 128 rows x 16 k, via float4, store transposed
#pragma unroll
    for (int it = 0; it < 2; ++it) {
      int idx = tid + it * 256;       // 0..511
      int r = idx >> 2;               // 0..127
      int c4 = (idx & 3) << 2;        // 0,4,8,12
      const float4 a4 = *(const float4*)(A + (size_t)(row0 + r) * K + (k0 + c4));
      As[c4 + 0][r] = a4.x; As[c4 + 1][r] = a4.y;
      As[c4 + 2][r] = a4.z; As[c4 + 3][r] = a4.w;
    }
    {
      int r = tid >> 4;               // 0..15
      int c4 = (tid & 15) << 2;       // 0..60
      const float4 b4 = *(const float4*)(B + (size_t)(k0 + r) * N + (col0 + c4));
      *(float4*)&Bs[r][c4] = b4;
    }
    __syncthreads();
#pragma unroll
    for (int kk = 0; kk < 16; ++kk) {
      float4 a0 = *(const float4*)&As[kk][ty * 8];
      float4 a1 = *(const float4*)&As[kk][ty * 8 + 4];
      float4 b0 = *(const float4*)&Bs[kk][tx * 4];
      float av[8] = {a0.x, a0.y, a0.z, a0.w, a1.x, a1.y, a1.z, a1.w};
      float bv4[4] = {b0.x, b0.y, b0.z, b0.w};
#pragma unroll
      for (int i = 0; i < 8; ++i)
#pragma unroll
        for (int j = 0; j < 4; ++j) acc[i][j] = fmaf(av[i], bv4[j], acc[i][j]);
    }
    __syncthreads();
  }

#pragma unroll
  for (int i = 0; i < 8; ++i) {
    int r = row0 + ty * 8 + i;
    size_t orow;
    if (KV) orow = (size_t)((r >> 10) * EXT_LEN + P_PAD + (r & (S_LEN - 1)));
    else    orow = (size_t)r;
#pragma unroll
    for (int j = 0; j < 4; ++j) {
      int c = col0 + tx * 4 + j;
      float v = acc[i][j] + bias[c];
      if (RELU) v = fmaxf(v, 0.f);
      C[orow * N + c] = v;
    }
  }
}

// ---------------- windowed attention ----------------
__device__ inline float dot512(const float* __restrict__ qs, const float* __restrict__ krow) {
  const float4* kp = (const float4*)krow;
  const float4* qp = (const float4*)qs;
  float a0 = 0.f, a1 = 0.f, a2 = 0.f, a3 = 0.f;
#pragma unroll 4
  for (int i = 0; i < 128; ++i) {
    float4 kv = kp[i];
    float4 qv = qp[i];
    a0 = fmaf(kv.x, qv.x, a0);
    a1 = fmaf(kv.y, qv.y, a1);
    a2 = fmaf(kv.z, qv.z, a2);
    a3 = fmaf(kv.w, qv.w, a3);
  }
  return (a0 + a1) + (a2 + a3);
}

__global__ __launch_bounds__(256) void attn_kernel(const float* __restrict__ q,
                                                   const float* __restrict__ k_ext,
                                                   const float* __restrict__ v_ext,
                                                   float* __restrict__ out) {
  const int bs = blockIdx.x;          // 0..2047
  const int b = bs >> 10;
  const int s = bs & (S_LEN - 1);
  const int tid = threadIdx.x;
  __shared__ float q_s[E_DIM];
  __shared__ float p_s[W_WIN];
  __shared__ float red[8];

  ((float2*)q_s)[tid] = ((const float2*)(q + (size_t)bs * E_DIM))[tid];
  __syncthreads();

  const float scale = 0.044194173824159216f;  // 1/sqrt(512)
  const size_t krow0 = (size_t)(b * EXT_LEN + s) * E_DIM;
  float e0v = dot512(q_s, k_ext + krow0 + (size_t)tid * E_DIM) * scale;
  float e1v = -1e30f;
  if (tid == 0) e1v = dot512(q_s, k_ext + krow0 + (size_t)256 * E_DIM) * scale;

  // block max
  float lm = wave_reduce_max(fmaxf(e0v, e1v));
  if ((tid & 63) == 0) red[tid >> 6] = lm;
  __syncthreads();
  const float M = fmaxf(fmaxf(red[0], red[1]), fmaxf(red[2], red[3]));

  // exp + sum
  float p0 = __expf(e0v - M);
  p_s[tid] = p0;
  float ls = p0;
  if (tid == 0) {
    float p1 = __expf(e1v - M);
    p_s[256] = p1;
    ls += p1;
  }
  ls = wave_reduce_sum(ls);
  if ((tid & 63) == 0) red[4 + (tid >> 6)] = ls;
  __syncthreads();  // covers p_s writes and red[4..7]
  const float inv = 1.0f / (red[4] + red[5] + red[6] + red[7]);

  // PV: thread owns columns 2*tid, 2*tid+1
  const int e0 = tid * 2;
  float acc0 = 0.f, acc1 = 0.f;
  const float* vbase = v_ext + (size_t)(b * EXT_LEN + s) * E_DIM + e0;
#pragma unroll 4
  for (int w = 0; w < W_WIN; ++w) {
    float p = p_s[w];
    float2 v2 = *(const float2*)(vbase + (size_t)w * E_DIM);
    acc0 = fmaf(p, v2.x, acc0);
    acc1 = fmaf(p, v2.y, acc1);
  }
  float2 o;
  o.x = acc0 * inv;
  o.y = acc1 * inv;
  *(float2*)(out + (size_t)bs * E_DIM + e0) = o;
}

// ---------------- residual + LayerNorm ----------------
__global__ __launch_bounds__(256) void ln_kernel(const float* __restrict__ a,
                                                 const float* __restrict__ rsd,
                                                 const float* __restrict__ w,
                                                 const float* __restrict__ bias,
                                                 float* __restrict__ out) {
  const int row = blockIdx.x;
  const int tid = threadIdx.x;
  __shared__ float red[8];
  const size_t base = (size_t)row * E_DIM + tid * 2;
  float2 av = *(const float2*)(a + base);
  float2 rv = *(const float2*)(rsd + base);
  float x0 = av.x + rv.x, x1 = av.y + rv.y;

  float sm = wave_reduce_sum(x0 + x1);
  if ((tid & 63) == 0) red[tid >> 6] = sm;
  __syncthreads();
  float mu = (red[0] + red[1] + red[2] + red[3]) * (1.0f / 512.0f);
  float d0 = x0 - mu, d1 = x1 - mu;
  float vs = wave_reduce_sum(d0 * d0 + d1 * d1);
  if ((tid & 63) == 0) red[4 + (tid >> 6)] = vs;
  __syncthreads();
  float var = (red[4] + red[5] + red[6] + red[7]) * (1.0f / 512.0f);
  float inv = rsqrtf(var + 1e-5f);
  float2 wv = *(const float2*)(w + tid * 2);
  float2 bi = *(const float2*)(bias + tid * 2);
  float2 o;
  o.x = d0 * inv * wv.x + bi.x;
  o.y = d1 * inv * wv.y + bi.y;
  *(float2*)(out + base) = o;
}

// ---------------- launch ----------------
extern "C" void kernel_launch(void* const* d_in, const int* in_sizes, int n_in,
                              void* d_out, int out_size, void* d_ws, size_t ws_size,
                              hipStream_t stream) {
  const float* x    = (const float*)d_in[0];
  const float* wq   = (const float*)d_in[1];
  const float* bq   = (const float*)d_in[2];
  const float* wk   = (const float*)d_in[3];
  const float* bk   = (const float*)d_in[4];
  const float* wv   = (const float*)d_in[5];
  const float* bv   = (const float*)d_in[6];
  const float* w1   = (const float*)d_in[7];
  const float* b1   = (const float*)d_in[8];
  const float* w2   = (const float*)d_in[9];
  const float* b2   = (const float*)d_in[10];
  const float* ln1w = (const float*)d_in[11];
  const float* ln1b = (const float*)d_in[12];
  const float* ln2w = (const float*)d_in[13];
  const float* ln2b = (const float*)d_in[14];

  float* ws = (float*)d_ws;
  // arena (floats): footprint 7,602,176 floats = 30.4 MB
  float* x_pe   = ws + 0;            // 1,048,576  live: ..LN1
  float* q      = ws + 1048576;      // 1,048,576  live: ..attn
  float* x1     = ws + 2097152;      // 1,048,576  (reuses k_ext slot after attn)
  float* k_ext  = ws + 2097152;      // 1,310,720  live: ..attn
  float* v_ext  = ws + 3407872;      // 1,310,720  live: ..attn
  float* attn_o = ws + 4718592;      // 1,048,576  live: ..LN1
  float* ff1    = ws + 3407872;      // 4,194,304  (reuses v_ext+attn_o after LN1)
  float* ff2    = ws + 0;            // 1,048,576  (reuses x_pe after LN1)

  pe_add_kernel<<<4096, 256, 0, stream>>>(x, x_pe);
  fill_pads_kernel<<<2048, 256, 0, stream>>>(bk, bv, k_ext, v_ext);

  gemm_kernel<false, false><<<dim3(8, 16), 256, 0, stream>>>(x_pe, wq, bq, q, BS_ROWS, E_DIM, E_DIM);
  gemm_kernel<false, true ><<<dim3(8, 16), 256, 0, stream>>>(x_pe, wk, bk, k_ext, BS_ROWS, E_DIM, E_DIM);
  gemm_kernel<false, true ><<<dim3(8, 16), 256, 0, stream>>>(x_pe, wv, bv, v_ext, BS_ROWS, E_DIM, E_DIM);

  attn_kernel<<<BS_ROWS, 256, 0, stream>>>(q, k_ext, v_ext, attn_o);
  ln_kernel<<<BS_ROWS, 256, 0, stream>>>(attn_o, x_pe, ln1w, ln1b, x1);

  gemm_kernel<true,  false><<<dim3(32, 16), 256, 0, stream>>>(x1, w1, b1, ff1, BS_ROWS, H_DIM, E_DIM);
  gemm_kernel<false, false><<<dim3(8, 16),  256, 0, stream>>>(ff1, w2, b2, ff2, BS_ROWS, E_DIM, H_DIM);
  ln_kernel<<<BS_ROWS, 256, 0, stream>>>(ff2, x1, ln2w, ln2b, (float*)d_out);
}

// Round 2
// 124.760 us; speedup vs baseline: 4.8732x; 4.8732x over previous
//
#include <hip/hip_runtime.h>
#include <hip/hip_bf16.h>

// B=2, S=1024, E=512, H=2048, P=128, W=257
#define S_LEN 1024
#define E_DIM 512
#define H_DIM 2048
#define P_PAD 128
#define W_WIN 257
#define EXTA 1296              // 128 front pad + 1024 + 128 back pad + 16 zero (for 288-wide band tiles)
#define BS_ROWS 2048

typedef __attribute__((ext_vector_type(8))) short bf16x8;
typedef __attribute__((ext_vector_type(4))) float f32x4;

__device__ inline ushort f2bf(float x) {
  union { float f; unsigned u; } c; c.f = x;
  unsigned u = c.u;
  u += 0x7fffu + ((u >> 16) & 1u);   // RNE
  return (ushort)(u >> 16);
}

__device__ inline void gload16(ushort* dst, const ushort* src) {
  __builtin_amdgcn_global_load_lds(
      (const __attribute__((address_space(1))) void*)src,
      (__attribute__((address_space(3))) void*)dst, 16, 0, 0);
}

// ---------------- PE add: fp32 + bf16 outputs ----------------
__global__ __launch_bounds__(256) void pe_add_kernel(const float* __restrict__ x,
                                                     float* __restrict__ xpe,
                                                     ushort* __restrict__ xpe_bf) {
  int idx = blockIdx.x * 256 + threadIdx.x;  // 2*1024*512
  int e = idx & (E_DIM - 1);
  int s = (idx >> 9) & (S_LEN - 1);
  const float c = -9.210340371976184f / 512.0f;
  float freq = expf((float)(e & ~1) * c);
  float ang = (float)s * freq;
  float pe = (e & 1) ? cosf(ang) : sinf(ang);
  float v = x[idx] + pe;
  xpe[idx] = v;
  xpe_bf[idx] = f2bf(v);
}

// ---------------- weight transpose+convert: W[K][N] fp32 -> WT[N][K] bf16 ----------------
__global__ __launch_bounds__(256) void transpose_bf16_kernel(const float* __restrict__ W,
                                                             ushort* __restrict__ WT,
                                                             int K, int N) {
  __shared__ float t[32][33];
  int lx = threadIdx.x & 31, ly = threadIdx.x >> 5;  // 32 x 8
  int n0 = blockIdx.x * 32, k0 = blockIdx.y * 32;
#pragma unroll
  for (int r = 0; r < 4; ++r)
    t[ly + r * 8][lx] = W[(size_t)(k0 + ly + r * 8) * N + n0 + lx];
  __syncthreads();
#pragma unroll
  for (int r = 0; r < 4; ++r)
    WT[(size_t)(n0 + ly + r * 8) * K + k0 + lx] = f2bf(t[lx][ly + r * 8]);
}

// ---------------- pad prep for k_bf (row-major) and v_t (transposed) ----------------
__global__ __launch_bounds__(256) void prep_pads_kernel(const float* __restrict__ bk,
                                                        const float* __restrict__ bv,
                                                        ushort* __restrict__ k_bf,
                                                        ushort* __restrict__ v_t) {
  int idx = blockIdx.x * 256 + threadIdx.x;  // 2 tensors * 2 batch * 272*512
  int t = idx / (2 * 272 * 512);
  int r2 = idx % (2 * 272 * 512);
  int b = r2 / (272 * 512);
  int r3 = r2 % (272 * 512);
  if (t == 0) {
    int rr = r3 >> 9;          // 0..271
    int e = r3 & 511;
    int row = rr < 128 ? rr : 1024 + rr;       // 0..127 front, 1152..1295 back
    float v = rr < 256 ? bk[e] : 0.f;
    k_bf[((size_t)b * EXTA + row) * 512 + e] = f2bf(v);
  } else {
    int n = r3 / 272;
    int jj = r3 % 272;
    int j = jj < 128 ? jj : 1024 + jj;
    float v = jj < 256 ? bv[n] : 0.f;
    v_t[((size_t)b * 512 + n) * EXTA + j] = f2bf(v);
  }
}

// ---------------- MFMA GEMM: C(MxN) = A(MxK,bf16) @ Bt(NxK,bf16)^T + bias ----------------
// OUT: 0 = fp32 C + bias; 1 = bf16 C + bias + relu; 2 = QKV routing
template <int BM, int BN, int WM, int WN, int OUT>
__global__ __launch_bounds__(256) void mfma_gemm(const ushort* __restrict__ A,
                                                 const ushort* __restrict__ Bt,
                                                 const float* __restrict__ bias,
                                                 const float* __restrict__ bias2,
                                                 const float* __restrict__ bias3,
                                                 void* __restrict__ Cout,
                                                 ushort* __restrict__ q_out,
                                                 ushort* __restrict__ k_out,
                                                 ushort* __restrict__ v_out,
                                                 int M, int N, int K) {
  constexpr int WAVES_N = BN / WN;
  constexpr int FM = WM / 16, FN = WN / 16;
  __shared__ ushort As[BM * 64];
  __shared__ ushort Bs[BN * 64];
  const int tid = threadIdx.x;
  const int lane = tid & 63;
  const int w = tid >> 6;
  const int wr = w / WAVES_N, wc = w % WAVES_N;
  const int l15 = lane & 15, lhi = lane >> 4;
  const int col0 = blockIdx.x * BN, row0 = blockIdx.y * BM;

  f32x4 acc[FM][FN] = {};

  for (int k0 = 0; k0 < K; k0 += 64) {
    // stage A,B: linear LDS dest, inverse-swizzled global source (T2, rule 21)
#pragma unroll
    for (int it = 0; it < BM / 32; ++it) {
      int u = it * 256 + tid;
      int r = u >> 3;
      int c16 = (u & 7) ^ (r & 7);
      gload16(&As[(size_t)u * 8], &A[(size_t)(row0 + r) * K + k0 + c16 * 8]);
    }
#pragma unroll
    for (int it = 0; it < BN / 32; ++it) {
      int u = it * 256 + tid;
      int r = u >> 3;
      int c16 = (u & 7) ^ (r & 7);
      gload16(&Bs[(size_t)u * 8], &Bt[(size_t)(col0 + r) * K + k0 + c16 * 8]);
    }
    __syncthreads();
#pragma unroll
    for (int kk = 0; kk < 2; ++kk) {
      bf16x8 af[FM], bfr[FN];
#pragma unroll
      for (int mi = 0; mi < FM; ++mi) {
        int r = wr * WM + mi * 16 + l15;
        int c16 = (kk * 4 + lhi) ^ (r & 7);
        af[mi] = *(const bf16x8*)&As[r * 64 + c16 * 8];
      }
#pragma unroll
      for (int ni = 0; ni < FN; ++ni) {
        int r = wc * WN + ni * 16 + l15;
        int c16 = (kk * 4 + lhi) ^ (r & 7);
        bfr[ni] = *(const bf16x8*)&Bs[r * 64 + c16 * 8];
      }
#pragma unroll
      for (int mi = 0; mi < FM; ++mi)
#pragma unroll
        for (int ni = 0; ni < FN; ++ni)
          acc[mi][ni] = __builtin_amdgcn_mfma_f32_16x16x32_bf16(af[mi], bfr[ni], acc[mi][ni], 0, 0, 0);
    }
    __syncthreads();
  }

#pragma unroll
  for (int mi = 0; mi < FM; ++mi) {
    int mbase = row0 + wr * WM + mi * 16 + lhi * 4;
#pragma unroll
    for (int ni = 0; ni < FN; ++ni) {
      int n = col0 + wc * WN + ni * 16 + l15;
      if constexpr (OUT == 0) {
        float b = bias[n];
        float* C = (float*)Cout;
#pragma unroll
        for (int j = 0; j < 4; ++j) C[(size_t)(mbase + j) * N + n] = acc[mi][ni][j] + b;
      } else if constexpr (OUT == 1) {
        float b = bias[n];
        ushort* C = (ushort*)Cout;
#pragma unroll
        for (int j = 0; j < 4; ++j) C[(size_t)(mbase + j) * N + n] = f2bf(fmaxf(acc[mi][ni][j] + b, 0.f));
      } else {
        int sect = n >> 9, nn = n & 511;
        float b = sect == 0 ? bias[nn] : (sect == 1 ? bias2[nn] : bias3[nn]);
        int bb = mbase >> 10;
        int s = mbase & 1023;
        if (sect == 0) {
#pragma unroll
          for (int j = 0; j < 4; ++j) q_out[(size_t)(mbase + j) * 512 + nn] = f2bf(acc[mi][ni][j] + b);
        } else if (sect == 1) {
#pragma unroll
          for (int j = 0; j < 4; ++j)
            k_out[((size_t)bb * EXTA + 128 + s + j) * 512 + nn] = f2bf(acc[mi][ni][j] + b);
        } else {
          ushort4 pk;
          pk.x = f2bf(acc[mi][ni][0] + b);
          pk.y = f2bf(acc[mi][ni][1] + b);
          pk.z = f2bf(acc[mi][ni][2] + b);
          pk.w = f2bf(acc[mi][ni][3] + b);
          *(ushort4*)&v_out[((size_t)bb * 512 + nn) * EXTA + 128 + s] = pk;
        }
      }
    }
  }
}

// ---------------- banded MFMA attention ----------------
// block = one 16-row q tile, 4 waves. energy 16x288 (masked), softmax in LDS, PV vs v_t.
__global__ __launch_bounds__(256) void attn_mfma(const ushort* __restrict__ qb,
                                                 const ushort* __restrict__ kb,
                                                 const ushort* __restrict__ vt,
                                                 float* __restrict__ out) {
  __shared__ float e_s[16][292];
  __shared__ ushort p_s[16][296];
  __shared__ float inv_s[16];
  const int tid = threadIdx.x;
  const int lane = tid & 63;
  const int w = tid >> 6;
  const int l15 = lane & 15, lhi = lane >> 4;
  const int tile = blockIdx.x;  // 0..127
  const int b = tile >> 6;
  const int s0 = (tile & 63) * 16;

  // Q fragments (row = l15, k chunk = lhi*8), reused across j-tiles
  const ushort* qrow = qb + (size_t)(b * 1024 + s0 + l15) * 512 + lhi * 8;
  bf16x8 qf[16];
#pragma unroll
  for (int ks = 0; ks < 16; ++ks) qf[ks] = *(const bf16x8*)(qrow + ks * 32);

  const float scale = 0.044194173824159216f;  // 1/sqrt(512)
  const ushort* kbase = kb + (size_t)b * EXTA * 512 + (size_t)(s0 + l15) * 512 + lhi * 8;

  // energy phase: wave w handles j-tiles w, w+4, ...
  for (int jt = w; jt < 18; jt += 4) {
    f32x4 acc = {};
    const ushort* kp = kbase + (size_t)jt * 16 * 512;
#pragma unroll
    for (int ks = 0; ks < 16; ++ks) {
      bf16x8 kf = *(const bf16x8*)(kp + ks * 32);
      acc = __builtin_amdgcn_mfma_f32_16x16x32_bf16(qf[ks], kf, acc, 0, 0, 0);
    }
    int jc = jt * 16 + l15;
#pragma unroll
    for (int j = 0; j < 4; ++j) {
      int i = lhi * 4 + j;
      bool valid = (jc >= i) && (jc <= i + 256);
      e_s[i][jc] = valid ? acc[j] * scale : -1e30f;
    }
  }
  __syncthreads();

  // softmax: thread t -> row r = t>>4, col offset c0 = t&15 (16 lanes per row)
  {
    int r = tid >> 4, c0 = tid & 15;
    float m = -1e30f;
#pragma unroll
    for (int t = 0; t < 18; ++t) m = fmaxf(m, e_s[r][c0 + 16 * t]);
    m = fmaxf(m, __shfl_xor(m, 1));
    m = fmaxf(m, __shfl_xor(m, 2));
    m = fmaxf(m, __shfl_xor(m, 4));
    m = fmaxf(m, __shfl_xor(m, 8));
    float s = 0.f;
#pragma unroll
    for (int t = 0; t < 18; ++t) {
      float p = __expf(e_s[r][c0 + 16 * t] - m);
      s += p;
      p_s[r][c0 + 16 * t] = f2bf(p);
    }
    s += __shfl_xor(s, 1);
    s += __shfl_xor(s, 2);
    s += __shfl_xor(s, 4);
    s += __shfl_xor(s, 8);
    if (c0 == 0) inv_s[r] = 1.0f / s;
  }
  __syncthreads();

  // PV: wave w handles n-tiles w*8 .. w*8+7
  bf16x8 pf[9];
#pragma unroll
  for (int ks = 0; ks < 9; ++ks) pf[ks] = *(const bf16x8*)&p_s[l15][ks * 32 + lhi * 8];
  float inv[4];
#pragma unroll
  for (int j = 0; j < 4; ++j) inv[j] = inv_s[lhi * 4 + j];

  const ushort* vbase = vt + (size_t)b * 512 * EXTA + s0 + lhi * 8;
  float* obase = out + (size_t)(b * 1024 + s0) * 512;
#pragma unroll
  for (int ni = 0; ni < 8; ++ni) {
    int n = w * 128 + ni * 16 + l15;
    f32x4 acc = {};
    const ushort* vp = vbase + (size_t)n * EXTA;
#pragma unroll
    for (int ks = 0; ks < 9; ++ks) {
      bf16x8 vf = *(const bf16x8*)(vp + ks * 32);
      acc = __builtin_amdgcn_mfma_f32_16x16x32_bf16(pf[ks], vf, acc, 0, 0, 0);
    }
#pragma unroll
    for (int j = 0; j < 4; ++j)
      obase[(size_t)(lhi * 4 + j) * 512 + n] = acc[j] * inv[j];
  }
}

// ---------------- residual + LayerNorm (fp32 out + optional bf16 out) ----------------
__device__ inline float wave_reduce_sum(float v) {
#pragma unroll
  for (int off = 32; off >= 1; off >>= 1) v += __shfl_xor(v, off);
  return v;
}

__global__ __launch_bounds__(256) void ln_kernel(const float* __restrict__ a,
                                                 const float* __restrict__ rsd,
                                                 const float* __restrict__ w,
                                                 const float* __restrict__ bias,
                                                 float* __restrict__ out,
                                                 ushort* __restrict__ out_bf) {
  const int row = blockIdx.x;
  const int tid = threadIdx.x;
  __shared__ float red[8];
  const size_t base = (size_t)row * E_DIM + tid * 2;
  float2 av = *(const float2*)(a + base);
  float2 rv = *(const float2*)(rsd + base);
  float x0 = av.x + rv.x, x1 = av.y + rv.y;

  float sm = wave_reduce_sum(x0 + x1);
  if ((tid & 63) == 0) red[tid >> 6] = sm;
  __syncthreads();
  float mu = (red[0] + red[1] + red[2] + red[3]) * (1.0f / 512.0f);
  float d0 = x0 - mu, d1 = x1 - mu;
  float vs = wave_reduce_sum(d0 * d0 + d1 * d1);
  if ((tid & 63) == 0) red[4 + (tid >> 6)] = vs;
  __syncthreads();
  float var = (red[4] + red[5] + red[6] + red[7]) * (1.0f / 512.0f);
  float inv = rsqrtf(var + 1e-5f);
  float2 wv = *(const float2*)(w + tid * 2);
  float2 bi = *(const float2*)(bias + tid * 2);
  float o0 = d0 * inv * wv.x + bi.x;
  float o1 = d1 * inv * wv.y + bi.y;
  *(float2*)(out + base) = make_float2(o0, o1);
  if (out_bf) {
    ushort2 ob;
    ob.x = f2bf(o0);
    ob.y = f2bf(o1);
    *(ushort2*)(out_bf + base) = ob;
  }
}

// ---------------- launch ----------------
extern "C" void kernel_launch(void* const* d_in, const int* in_sizes, int n_in,
                              void* d_out, int out_size, void* d_ws, size_t ws_size,
                              hipStream_t stream) {
  const float* x    = (const float*)d_in[0];
  const float* wq   = (const float*)d_in[1];
  const float* bq   = (const float*)d_in[2];
  const float* wk   = (const float*)d_in[3];
  const float* bk   = (const float*)d_in[4];
  const float* wv   = (const float*)d_in[5];
  const float* bv   = (const float*)d_in[6];
  const float* w1   = (const float*)d_in[7];
  const float* b1   = (const float*)d_in[8];
  const float* w2   = (const float*)d_in[9];
  const float* b2   = (const float*)d_in[10];
  const float* ln1w = (const float*)d_in[11];
  const float* ln1b = (const float*)d_in[12];
  const float* ln2w = (const float*)d_in[13];
  const float* ln2b = (const float*)d_in[14];

  char* W = (char*)d_ws;
  float*  x_pe   = (float*)(W);                      // [0,4M)
  float*  attn_o = (float*)(W + (4u << 20));         // [4,8M)
  ushort* xpebf  = (ushort*)(W + (8u << 20));        // [8,10M)
  ushort* wqkvT  = (ushort*)(W + (10u << 20));       // [10,11.5M)
  ushort* w1T    = (ushort*)(W + (23u << 19));       // [11.5,13.5M)
  ushort* w2T    = (ushort*)(W + (27u << 19));       // [13.5,15.5M)
  ushort* q_bf   = (ushort*)(W + (31u << 19));       // [15.5,17.5M)
  ushort* k_bf   = (ushort*)(W + (35u << 19));       // [17.5,~20.03M)
  ushort* v_t    = (ushort*)(W + (81u << 18));       // [20.25,~22.78M)
  float*  x1     = (float*)(W + (23u << 20));        // [23,27M)
  ushort* x1bf   = (ushort*)(W + (27u << 20));       // [27,29M)
  ushort* ff1_bf = (ushort*)(W);                     // [0,8M)   after LN1
  float*  ff2    = (float*)(W + (8u << 20));         // [8,12M)  after QKV/FFN1

  // weight transposes -> bf16 [N][K]
  transpose_bf16_kernel<<<dim3(16, 16), 256, 0, stream>>>(wq, wqkvT, 512, 512);
  transpose_bf16_kernel<<<dim3(16, 16), 256, 0, stream>>>(wk, wqkvT + 512 * 512, 512, 512);
  transpose_bf16_kernel<<<dim3(16, 16), 256, 0, stream>>>(wv, wqkvT + 1024 * 512, 512, 512);
  transpose_bf16_kernel<<<dim3(64, 16), 256, 0, stream>>>(w1, w1T, 512, 2048);
  transpose_bf16_kernel<<<dim3(16, 64), 256, 0, stream>>>(w2, w2T, 2048, 512);

  pe_add_kernel<<<4096, 256, 0, stream>>>(x, x_pe, xpebf);
  prep_pads_kernel<<<2176, 256, 0, stream>>>(bk, bv, k_bf, v_t);

  // QKV fused: M=2048, N=1536, K=512
  mfma_gemm<128, 128, 64, 64, 2><<<dim3(12, 16), 256, 0, stream>>>(
      xpebf, wqkvT, bq, bk, bv, nullptr, q_bf, k_bf, v_t, BS_ROWS, 1536, 512);

  attn_mfma<<<128, 256, 0, stream>>>(q_bf, k_bf, v_t, attn_o);
  ln_kernel<<<BS_ROWS, 256, 0, stream>>>(attn_o, x_pe, ln1w, ln1b, x1, x1bf);

  // FFN1: M=2048, N=2048, K=512, relu, bf16 out
  mfma_gemm<128, 128, 64, 64, 1><<<dim3(16, 16), 256, 0, stream>>>(
      x1bf, w1T, b1, nullptr, nullptr, ff1_bf, nullptr, nullptr, nullptr, BS_ROWS, H_DIM, 512);

  // FFN2: M=2048, N=512, K=2048, fp32 out
  mfma_gemm<64, 64, 32, 32, 0><<<dim3(8, 32), 256, 0, stream>>>(
      ff1_bf, w2T, b2, nullptr, nullptr, ff2, nullptr, nullptr, nullptr, BS_ROWS, E_DIM, H_DIM);

  ln_kernel<<<BS_ROWS, 256, 0, stream>>>(ff2, x1, ln2w, ln2b, (float*)d_out, nullptr);
}

// Round 3
// 83.822 us; speedup vs baseline: 7.2533x; 1.4884x over previous
//
#include <hip/hip_runtime.h>
#include <hip/hip_bf16.h>

// B=2, S=1024, E=512, H=2048, P=128, W=257
#define S_LEN 1024
#define E_DIM 512
#define H_DIM 2048
#define P_PAD 128
#define EXTA 1296              // 128 front pad + 1024 + 128 back pad + 16 zeros (band tiles)
#define BS_ROWS 2048

typedef __attribute__((ext_vector_type(8))) short bf16x8;
typedef __attribute__((ext_vector_type(4))) float f32x4;

__device__ inline ushort f2bf(float x) {
  union { float f; unsigned u; } c; c.f = x;
  unsigned u = c.u;
  u += 0x7fffu + ((u >> 16) & 1u);   // RNE
  return (ushort)(u >> 16);
}

__device__ inline void gload16(ushort* dst, const ushort* src) {
  __builtin_amdgcn_global_load_lds(
      (const __attribute__((address_space(1))) void*)src,
      (__attribute__((address_space(3))) void*)dst, 16, 0, 0);
}

// ---------------- all weight transposes fused: W[K][N] fp32 -> WT[N][K] bf16 ----------------
// tiles: [0,256) wq, [256,512) wk, [512,768) wv, [768,1792) w1, [1792,2816) w2
__global__ __launch_bounds__(256) void transpose_all_kernel(const float* __restrict__ wq,
                                                            const float* __restrict__ wk,
                                                            const float* __restrict__ wv,
                                                            const float* __restrict__ w1,
                                                            const float* __restrict__ w2,
                                                            ushort* __restrict__ wqkvT,
                                                            ushort* __restrict__ w1T,
                                                            ushort* __restrict__ w2T) {
  __shared__ float t[32][33];
  const int tile = blockIdx.x;
  const float* W; ushort* WT; int K, N, bx, by;
  if (tile < 768) {
    K = 512; N = 512;
    int sect = tile >> 8, tt = tile & 255;
    W = sect == 0 ? wq : (sect == 1 ? wk : wv);
    WT = wqkvT + (size_t)sect * 512 * 512;
    bx = tt & 15; by = tt >> 4;
  } else if (tile < 1792) {
    K = 512; N = 2048; W = w1; WT = w1T;
    int tt = tile - 768; bx = tt & 63; by = tt >> 6;
  } else {
    K = 2048; N = 512; W = w2; WT = w2T;
    int tt = tile - 1792; bx = tt & 15; by = tt >> 4;
  }
  int lx = threadIdx.x & 31, ly = threadIdx.x >> 5;  // 32 x 8
  int n0 = bx * 32, k0 = by * 32;
#pragma unroll
  for (int r = 0; r < 4; ++r)
    t[ly + r * 8][lx] = W[(size_t)(k0 + ly + r * 8) * N + n0 + lx];
  __syncthreads();
#pragma unroll
  for (int r = 0; r < 4; ++r)
    WT[(size_t)(n0 + ly + r * 8) * K + k0 + lx] = f2bf(t[lx][ly + r * 8]);
}

// ---------------- fused PE add (fp32+bf16) and pad fill ----------------
__global__ __launch_bounds__(256) void pe_pad_kernel(const float* __restrict__ x,
                                                     const float* __restrict__ bk,
                                                     const float* __restrict__ bv,
                                                     float* __restrict__ xpe,
                                                     ushort* __restrict__ xpe_bf,
                                                     ushort* __restrict__ k_bf,
                                                     ushort* __restrict__ v_t) {
  int idx = blockIdx.x * 256 + threadIdx.x;
  if (idx < BS_ROWS * E_DIM) {
    int e = idx & (E_DIM - 1);
    int s = (idx >> 9) & (S_LEN - 1);
    const float c = -9.210340371976184f / 512.0f;
    float freq = expf((float)(e & ~1) * c);
    float ang = (float)s * freq;
    float pe = (e & 1) ? cosf(ang) : sinf(ang);
    float v = x[idx] + pe;
    xpe[idx] = v;
    xpe_bf[idx] = f2bf(v);
  } else {
    int p = idx - BS_ROWS * E_DIM;       // 2 tensors * 2 batch * 272 * 512
    int t = p / (2 * 272 * 512);
    int r2 = p % (2 * 272 * 512);
    int b = r2 / (272 * 512);
    int r3 = r2 % (272 * 512);
    if (t == 0) {
      int rr = r3 >> 9, e = r3 & 511;
      int row = rr < 128 ? rr : 1024 + rr;   // front 0..127, back 1152..1279, zeros 1280..1295
      float v = rr < 256 ? bk[e] : 0.f;
      k_bf[((size_t)b * EXTA + row) * 512 + e] = f2bf(v);
    } else {
      int n = r3 / 272, jj = r3 % 272;
      int j = jj < 128 ? jj : 1024 + jj;
      float v = jj < 256 ? bv[n] : 0.f;
      v_t[((size_t)b * 512 + n) * EXTA + j] = f2bf(v);
    }
  }
}

// ---------------- MFMA GEMM: C(MxN) = A(MxK bf16) @ Bt(NxK bf16)^T ----------------
// OUT: 0 = fp32+bias; 1 = bf16+bias+relu; 2 = QKV routing; 3 = fp32 partial (split-K, no bias)
template <int BM, int BN, int WM, int WN, int OUT>
__global__ __launch_bounds__(256) void mfma_gemm(const ushort* __restrict__ A,
                                                 const ushort* __restrict__ Bt,
                                                 const float* __restrict__ bias,
                                                 const float* __restrict__ bias2,
                                                 const float* __restrict__ bias3,
                                                 void* __restrict__ Cout,
                                                 ushort* __restrict__ q_out,
                                                 ushort* __restrict__ k_out,
                                                 ushort* __restrict__ v_out,
                                                 int M, int N, int K, int LDA) {
  constexpr int WAVES_N = BN / WN;
  constexpr int FM = WM / 16, FN = WN / 16;
  __shared__ ushort As[BM * 64];
  __shared__ ushort Bs[BN * 64];
  const int tid = threadIdx.x;
  const int lane = tid & 63;
  const int w = tid >> 6;
  const int wr = w / WAVES_N, wc = w % WAVES_N;
  const int l15 = lane & 15, lhi = lane >> 4;
  const int col0 = blockIdx.x * BN, row0 = blockIdx.y * BM;
  const int koff = blockIdx.z * K;

  f32x4 acc[FM][FN] = {};

  for (int k0 = 0; k0 < K; k0 += 64) {
#pragma unroll
    for (int it = 0; it < BM / 32; ++it) {
      int u = it * 256 + tid;
      int r = u >> 3;
      int c16 = (u & 7) ^ (r & 7);
      gload16(&As[(size_t)u * 8], &A[(size_t)(row0 + r) * LDA + koff + k0 + c16 * 8]);
    }
#pragma unroll
    for (int it = 0; it < BN / 32; ++it) {
      int u = it * 256 + tid;
      int r = u >> 3;
      int c16 = (u & 7) ^ (r & 7);
      gload16(&Bs[(size_t)u * 8], &Bt[(size_t)(col0 + r) * LDA + koff + k0 + c16 * 8]);
    }
    __syncthreads();
#pragma unroll
    for (int kk = 0; kk < 2; ++kk) {
      bf16x8 af[FM], bfr[FN];
#pragma unroll
      for (int mi = 0; mi < FM; ++mi) {
        int r = wr * WM + mi * 16 + l15;
        int c16 = (kk * 4 + lhi) ^ (r & 7);
        af[mi] = *(const bf16x8*)&As[r * 64 + c16 * 8];
      }
#pragma unroll
      for (int ni = 0; ni < FN; ++ni) {
        int r = wc * WN + ni * 16 + l15;
        int c16 = (kk * 4 + lhi) ^ (r & 7);
        bfr[ni] = *(const bf16x8*)&Bs[r * 64 + c16 * 8];
      }
#pragma unroll
      for (int mi = 0; mi < FM; ++mi)
#pragma unroll
        for (int ni = 0; ni < FN; ++ni)
          acc[mi][ni] = __builtin_amdgcn_mfma_f32_16x16x32_bf16(af[mi], bfr[ni], acc[mi][ni], 0, 0, 0);
    }
    __syncthreads();
  }

#pragma unroll
  for (int mi = 0; mi < FM; ++mi) {
    int mbase = row0 + wr * WM + mi * 16 + lhi * 4;
#pragma unroll
    for (int ni = 0; ni < FN; ++ni) {
      int n = col0 + wc * WN + ni * 16 + l15;
      if constexpr (OUT == 0) {
        float b = bias[n];
        float* C = (float*)Cout;
#pragma unroll
        for (int j = 0; j < 4; ++j) C[(size_t)(mbase + j) * N + n] = acc[mi][ni][j] + b;
      } else if constexpr (OUT == 1) {
        float b = bias[n];
        ushort* C = (ushort*)Cout;
#pragma unroll
        for (int j = 0; j < 4; ++j) C[(size_t)(mbase + j) * N + n] = f2bf(fmaxf(acc[mi][ni][j] + b, 0.f));
      } else if constexpr (OUT == 3) {
        float* C = (float*)Cout + (size_t)blockIdx.z * M * N;
#pragma unroll
        for (int j = 0; j < 4; ++j) C[(size_t)(mbase + j) * N + n] = acc[mi][ni][j];
      } else {
        int sect = n >> 9, nn = n & 511;
        float b = sect == 0 ? bias[nn] : (sect == 1 ? bias2[nn] : bias3[nn]);
        int bb = mbase >> 10;
        int s = mbase & 1023;
        if (sect == 0) {
#pragma unroll
          for (int j = 0; j < 4; ++j) q_out[(size_t)(mbase + j) * 512 + nn] = f2bf(acc[mi][ni][j] + b);
        } else if (sect == 1) {
#pragma unroll
          for (int j = 0; j < 4; ++j)
            k_out[((size_t)bb * EXTA + 128 + s + j) * 512 + nn] = f2bf(acc[mi][ni][j] + b);
        } else {
          ushort4 pk;
          pk.x = f2bf(acc[mi][ni][0] + b);
          pk.y = f2bf(acc[mi][ni][1] + b);
          pk.z = f2bf(acc[mi][ni][2] + b);
          pk.w = f2bf(acc[mi][ni][3] + b);
          *(ushort4*)&v_out[((size_t)bb * 512 + nn) * EXTA + 128 + s] = pk;
        }
      }
    }
  }
}

// ---------------- banded MFMA attention: 8 waves / 16-row q-tile ----------------
__global__ __launch_bounds__(512) void attn_mfma(const ushort* __restrict__ qb,
                                                 const ushort* __restrict__ kb,
                                                 const ushort* __restrict__ vt,
                                                 float* __restrict__ out) {
  __shared__ float e_s[16][292];
  __shared__ ushort p_s[16][296];
  __shared__ float inv_s[16];
  const int tid = threadIdx.x;
  const int lane = tid & 63;
  const int w = tid >> 6;          // 0..7
  const int l15 = lane & 15, lhi = lane >> 4;
  const int tile = blockIdx.x;     // 0..127
  const int b = tile >> 6;
  const int s0 = (tile & 63) * 16;

  const ushort* qrow = qb + (size_t)(b * 1024 + s0 + l15) * 512 + lhi * 8;
  bf16x8 qf[16];
#pragma unroll
  for (int ks = 0; ks < 16; ++ks) qf[ks] = *(const bf16x8*)(qrow + ks * 32);

  const float scale = 0.044194173824159216f;  // 1/sqrt(512)
  const ushort* kbase = kb + (size_t)b * EXTA * 512 + (size_t)(s0 + l15) * 512 + lhi * 8;

  // energy: wave w -> j-tiles {w, w+8, w+16}
  for (int jt = w; jt < 18; jt += 8) {
    f32x4 acc = {};
    const ushort* kp = kbase + (size_t)jt * 16 * 512;
#pragma unroll
    for (int ks = 0; ks < 16; ++ks) {
      bf16x8 kf = *(const bf16x8*)(kp + ks * 32);
      acc = __builtin_amdgcn_mfma_f32_16x16x32_bf16(qf[ks], kf, acc, 0, 0, 0);
    }
    int jc = jt * 16 + l15;
#pragma unroll
    for (int j = 0; j < 4; ++j) {
      int i = lhi * 4 + j;
      bool valid = (jc >= i) && (jc <= i + 256);
      e_s[i][jc] = valid ? acc[j] * scale : -1e30f;
    }
  }
  __syncthreads();

  // softmax: row r = tid>>5, 32 lanes per row over 288 cols
  {
    int r = tid >> 5, c0 = tid & 31;
    float m = -1e30f;
#pragma unroll
    for (int t = 0; t < 9; ++t) m = fmaxf(m, e_s[r][c0 + 32 * t]);
#pragma unroll
    for (int off = 1; off <= 16; off <<= 1) m = fmaxf(m, __shfl_xor(m, off));
    float s = 0.f;
#pragma unroll
    for (int t = 0; t < 9; ++t) {
      float p = __expf(e_s[r][c0 + 32 * t] - m);
      s += p;
      p_s[r][c0 + 32 * t] = f2bf(p);
    }
#pragma unroll
    for (int off = 1; off <= 16; off <<= 1) s += __shfl_xor(s, off);
    if (c0 == 0) inv_s[r] = 1.0f / s;
  }
  __syncthreads();

  // PV: wave w -> n-tiles w*4 .. w*4+3
  bf16x8 pf[9];
#pragma unroll
  for (int ks = 0; ks < 9; ++ks) pf[ks] = *(const bf16x8*)&p_s[l15][ks * 32 + lhi * 8];
  float inv[4];
#pragma unroll
  for (int j = 0; j < 4; ++j) inv[j] = inv_s[lhi * 4 + j];

  const ushort* vbase = vt + (size_t)b * 512 * EXTA + s0 + lhi * 8;
  float* obase = out + (size_t)(b * 1024 + s0) * 512;
#pragma unroll
  for (int ni = 0; ni < 4; ++ni) {
    int n = w * 64 + ni * 16 + l15;
    f32x4 acc = {};
    const ushort* vp = vbase + (size_t)n * EXTA;
#pragma unroll
    for (int ks = 0; ks < 9; ++ks) {
      bf16x8 vf = *(const bf16x8*)(vp + ks * 32);
      acc = __builtin_amdgcn_mfma_f32_16x16x32_bf16(pf[ks], vf, acc, 0, 0, 0);
    }
#pragma unroll
    for (int j = 0; j < 4; ++j)
      obase[(size_t)(lhi * 4 + j) * 512 + n] = acc[j] * inv[j];
  }
}

// ---------------- residual + LayerNorm (a [+ a2 + ab] + rsd) ----------------
__device__ inline float wave_reduce_sum(float v) {
#pragma unroll
  for (int off = 32; off >= 1; off >>= 1) v += __shfl_xor(v, off);
  return v;
}

__global__ __launch_bounds__(256) void ln_kernel(const float* __restrict__ a,
                                                 const float* __restrict__ a2,
                                                 const float* __restrict__ ab,
                                                 const float* __restrict__ rsd,
                                                 const float* __restrict__ w,
                                                 const float* __restrict__ bias,
                                                 float* __restrict__ out,
                                                 ushort* __restrict__ out_bf) {
  const int row = blockIdx.x;
  const int tid = threadIdx.x;
  __shared__ float red[8];
  const int e0 = tid * 2;
  const size_t base = (size_t)row * E_DIM + e0;
  float2 av = *(const float2*)(a + base);
  float2 rv = *(const float2*)(rsd + base);
  float x0 = av.x + rv.x, x1 = av.y + rv.y;
  if (a2) {
    float2 v2 = *(const float2*)(a2 + base);
    x0 += v2.x; x1 += v2.y;
  }
  if (ab) {
    float2 bb = *(const float2*)(ab + e0);
    x0 += bb.x; x1 += bb.y;
  }

  float sm = wave_reduce_sum(x0 + x1);
  if ((tid & 63) == 0) red[tid >> 6] = sm;
  __syncthreads();
  float mu = (red[0] + red[1] + red[2] + red[3]) * (1.0f / 512.0f);
  float d0 = x0 - mu, d1 = x1 - mu;
  float vs = wave_reduce_sum(d0 * d0 + d1 * d1);
  if ((tid & 63) == 0) red[4 + (tid >> 6)] = vs;
  __syncthreads();
  float var = (red[4] + red[5] + red[6] + red[7]) * (1.0f / 512.0f);
  float inv = rsqrtf(var + 1e-5f);
  float2 wv = *(const float2*)(w + e0);
  float2 bi = *(const float2*)(bias + e0);
  float o0 = d0 * inv * wv.x + bi.x;
  float o1 = d1 * inv * wv.y + bi.y;
  *(float2*)(out + base) = make_float2(o0, o1);
  if (out_bf) {
    ushort2 ob;
    ob.x = f2bf(o0);
    ob.y = f2bf(o1);
    *(ushort2*)(out_bf + base) = ob;
  }
}

// ---------------- launch ----------------
extern "C" void kernel_launch(void* const* d_in, const int* in_sizes, int n_in,
                              void* d_out, int out_size, void* d_ws, size_t ws_size,
                              hipStream_t stream) {
  const float* x    = (const float*)d_in[0];
  const float* wq   = (const float*)d_in[1];
  const float* bq   = (const float*)d_in[2];
  const float* wk   = (const float*)d_in[3];
  const float* bk   = (const float*)d_in[4];
  const float* wv   = (const float*)d_in[5];
  const float* bv   = (const float*)d_in[6];
  const float* w1   = (const float*)d_in[7];
  const float* b1   = (const float*)d_in[8];
  const float* w2   = (const float*)d_in[9];
  const float* b2   = (const float*)d_in[10];
  const float* ln1w = (const float*)d_in[11];
  const float* ln1b = (const float*)d_in[12];
  const float* ln2w = (const float*)d_in[13];
  const float* ln2b = (const float*)d_in[14];

  char* W = (char*)d_ws;   // ws is 256MB; flat layout, no reuse needed
  float*  x_pe   = (float*)(W);                      // 4MB  @0
  float*  attn_o = (float*)(W + (4u  << 20));        // 4MB  @4
  ushort* xpebf  = (ushort*)(W + (8u  << 20));       // 2MB  @8
  ushort* wqkvT  = (ushort*)(W + (10u << 20));       // 1.5MB@10
  ushort* w1T    = (ushort*)(W + (12u << 20));       // 2MB  @12
  ushort* w2T    = (ushort*)(W + (14u << 20));       // 2MB  @14
  ushort* q_bf   = (ushort*)(W + (16u << 20));       // 2MB  @16
  ushort* k_bf   = (ushort*)(W + (18u << 20));       // 2.6MB@18
  ushort* v_t    = (ushort*)(W + (21u << 20));       // 2.6MB@21
  float*  x1     = (float*)(W + (24u << 20));        // 4MB  @24
  ushort* x1bf   = (ushort*)(W + (28u << 20));       // 2MB  @28
  ushort* ff1_bf = (ushort*)(W + (30u << 20));       // 8MB  @30
  float*  ff2    = (float*)(W + (38u << 20));        // 2x4MB@38 (split-K partials)

  transpose_all_kernel<<<2816, 256, 0, stream>>>(wq, wk, wv, w1, w2, wqkvT, w1T, w2T);
  pe_pad_kernel<<<6272, 256, 0, stream>>>(x, bk, bv, x_pe, xpebf, k_bf, v_t);

  // QKV fused: M=2048, N=1536, K=512
  mfma_gemm<64, 128, 32, 64, 2><<<dim3(12, 32), 256, 0, stream>>>(
      xpebf, wqkvT, bq, bk, bv, nullptr, q_bf, k_bf, v_t, BS_ROWS, 1536, 512, 512);

  attn_mfma<<<128, 512, 0, stream>>>(q_bf, k_bf, v_t, attn_o);
  ln_kernel<<<BS_ROWS, 256, 0, stream>>>(attn_o, nullptr, nullptr, x_pe, ln1w, ln1b, x1, x1bf);

  // FFN1: M=2048, N=2048, K=512, relu, bf16 out
  mfma_gemm<64, 128, 32, 64, 1><<<dim3(16, 32), 256, 0, stream>>>(
      x1bf, w1T, b1, nullptr, nullptr, ff1_bf, nullptr, nullptr, nullptr, BS_ROWS, H_DIM, 512, 512);

  // FFN2: M=2048, N=512, K=2048 split-K x2 -> fp32 partials
  mfma_gemm<64, 64, 32, 32, 3><<<dim3(8, 32, 2), 256, 0, stream>>>(
      ff1_bf, w2T, nullptr, nullptr, nullptr, ff2, nullptr, nullptr, nullptr, BS_ROWS, E_DIM, 1024, 2048);

  // LN2: (ff2a + ff2b + b2) + x1 residual
  ln_kernel<<<BS_ROWS, 256, 0, stream>>>(ff2, ff2 + (size_t)BS_ROWS * E_DIM, b2, x1,
                                         ln2w, ln2b, (float*)d_out, nullptr);
}

// Round 4
// 77.079 us; speedup vs baseline: 7.8878x; 1.0875x over previous
//
#include <hip/hip_runtime.h>
#include <hip/hip_bf16.h>

// B=2, S=1024, E=512, H=2048, P=128, W=257
#define S_LEN 1024
#define E_DIM 512
#define H_DIM 2048
#define P_PAD 128
#define EXTA 1296              // 128 front pad + 1024 + 128 back pad + 16 zeros (band tiles)
#define BS_ROWS 2048

typedef __attribute__((ext_vector_type(8))) short bf16x8;
typedef __attribute__((ext_vector_type(4))) float f32x4;

__device__ inline ushort f2bf(float x) {
  union { float f; unsigned u; } c; c.f = x;
  unsigned u = c.u;
  u += 0x7fffu + ((u >> 16) & 1u);   // RNE
  return (ushort)(u >> 16);
}

__device__ inline void gload16(ushort* dst, const ushort* src) {
  __builtin_amdgcn_global_load_lds(
      (const __attribute__((address_space(1))) void*)src,
      (__attribute__((address_space(3))) void*)dst, 16, 0, 0);
}

// ---------------- prep: PE add, pad fill, all weight transposes ----------------
// blocks [0,4096): PE; [4096,6272): pads; [6272,9088): transposes
__global__ __launch_bounds__(256) void prep_kernel(const float* __restrict__ x,
                                                   const float* __restrict__ bk,
                                                   const float* __restrict__ bv,
                                                   const float* __restrict__ wq,
                                                   const float* __restrict__ wk,
                                                   const float* __restrict__ wv,
                                                   const float* __restrict__ w1,
                                                   const float* __restrict__ w2,
                                                   float* __restrict__ xpe,
                                                   ushort* __restrict__ xpe_bf,
                                                   ushort* __restrict__ k_bf,
                                                   ushort* __restrict__ v_t,
                                                   ushort* __restrict__ wqkvT,
                                                   ushort* __restrict__ w1T,
                                                   ushort* __restrict__ w2T) {
  __shared__ float t[32][33];
  const int blk = blockIdx.x;
  if (blk < 4096) {
    int idx = blk * 256 + threadIdx.x;   // 2048*512
    int e = idx & (E_DIM - 1);
    int s = (idx >> 9) & (S_LEN - 1);
    const float c = -9.210340371976184f / 512.0f;
    float freq = expf((float)(e & ~1) * c);
    float ang = (float)s * freq;
    float pe = (e & 1) ? cosf(ang) : sinf(ang);
    float v = x[idx] + pe;
    xpe[idx] = v;
    xpe_bf[idx] = f2bf(v);
  } else if (blk < 6272) {
    int p = (blk - 4096) * 256 + threadIdx.x;  // 2 tensors * 2 batch * 272 * 512
    int t2 = p / (2 * 272 * 512);
    int r2 = p % (2 * 272 * 512);
    int b = r2 / (272 * 512);
    int r3 = r2 % (272 * 512);
    if (t2 == 0) {
      int rr = r3 >> 9, e = r3 & 511;
      int row = rr < 128 ? rr : 1024 + rr;   // front 0..127, back 1152..1279, zeros 1280..1295
      float v = rr < 256 ? bk[e] : 0.f;
      k_bf[((size_t)b * EXTA + row) * 512 + e] = f2bf(v);
    } else {
      int n = r3 / 272, jj = r3 % 272;
      int j = jj < 128 ? jj : 1024 + jj;
      float v = jj < 256 ? bv[n] : 0.f;
      v_t[((size_t)b * 512 + n) * EXTA + j] = f2bf(v);
    }
  } else {
    const int tile = blk - 6272;           // 0..2815
    const float* W; ushort* WT; int K, N, bx, by;
    if (tile < 768) {
      K = 512; N = 512;
      int sect = tile >> 8, tt = tile & 255;
      W = sect == 0 ? wq : (sect == 1 ? wk : wv);
      WT = wqkvT + (size_t)sect * 512 * 512;
      bx = tt & 15; by = tt >> 4;
    } else if (tile < 1792) {
      K = 512; N = 2048; W = w1; WT = w1T;
      int tt = tile - 768; bx = tt & 63; by = tt >> 6;
    } else {
      K = 2048; N = 512; W = w2; WT = w2T;
      int tt = tile - 1792; bx = tt & 15; by = tt >> 4;
    }
    int lx = threadIdx.x & 31, ly = threadIdx.x >> 5;  // 32 x 8
    int n0 = bx * 32, k0 = by * 32;
#pragma unroll
    for (int r = 0; r < 4; ++r)
      t[ly + r * 8][lx] = W[(size_t)(k0 + ly + r * 8) * N + n0 + lx];
    __syncthreads();
#pragma unroll
    for (int r = 0; r < 4; ++r)
      WT[(size_t)(n0 + ly + r * 8) * K + k0 + lx] = f2bf(t[lx][ly + r * 8]);
  }
}

// ---------------- MFMA GEMM: C(MxN) = A(MxK bf16) @ Bt(NxK bf16)^T ----------------
// OUT: 1 = bf16+bias+relu; 2 = QKV routing; 3 = fp32 partial (split-K, no bias)
template <int BM, int BN, int WM, int WN, int OUT>
__global__ __launch_bounds__(256) void mfma_gemm(const ushort* __restrict__ A,
                                                 const ushort* __restrict__ Bt,
                                                 const float* __restrict__ bias,
                                                 const float* __restrict__ bias2,
                                                 const float* __restrict__ bias3,
                                                 void* __restrict__ Cout,
                                                 ushort* __restrict__ q_out,
                                                 ushort* __restrict__ k_out,
                                                 ushort* __restrict__ v_out,
                                                 int M, int N, int K, int LDA) {
  constexpr int WAVES_N = BN / WN;
  constexpr int FM = WM / 16, FN = WN / 16;
  __shared__ ushort As[BM * 64];
  __shared__ ushort Bs[BN * 64];
  const int tid = threadIdx.x;
  const int lane = tid & 63;
  const int w = tid >> 6;
  const int wr = w / WAVES_N, wc = w % WAVES_N;
  const int l15 = lane & 15, lhi = lane >> 4;
  const int col0 = blockIdx.x * BN, row0 = blockIdx.y * BM;
  const int koff = blockIdx.z * K;

  f32x4 acc[FM][FN] = {};

  for (int k0 = 0; k0 < K; k0 += 64) {
#pragma unroll
    for (int it = 0; it < BM / 32; ++it) {
      int u = it * 256 + tid;
      int r = u >> 3;
      int c16 = (u & 7) ^ (r & 7);
      gload16(&As[(size_t)u * 8], &A[(size_t)(row0 + r) * LDA + koff + k0 + c16 * 8]);
    }
#pragma unroll
    for (int it = 0; it < BN / 32; ++it) {
      int u = it * 256 + tid;
      int r = u >> 3;
      int c16 = (u & 7) ^ (r & 7);
      gload16(&Bs[(size_t)u * 8], &Bt[(size_t)(col0 + r) * LDA + koff + k0 + c16 * 8]);
    }
    __syncthreads();
#pragma unroll
    for (int kk = 0; kk < 2; ++kk) {
      bf16x8 af[FM], bfr[FN];
#pragma unroll
      for (int mi = 0; mi < FM; ++mi) {
        int r = wr * WM + mi * 16 + l15;
        int c16 = (kk * 4 + lhi) ^ (r & 7);
        af[mi] = *(const bf16x8*)&As[r * 64 + c16 * 8];
      }
#pragma unroll
      for (int ni = 0; ni < FN; ++ni) {
        int r = wc * WN + ni * 16 + l15;
        int c16 = (kk * 4 + lhi) ^ (r & 7);
        bfr[ni] = *(const bf16x8*)&Bs[r * 64 + c16 * 8];
      }
#pragma unroll
      for (int mi = 0; mi < FM; ++mi)
#pragma unroll
        for (int ni = 0; ni < FN; ++ni)
          acc[mi][ni] = __builtin_amdgcn_mfma_f32_16x16x32_bf16(af[mi], bfr[ni], acc[mi][ni], 0, 0, 0);
    }
    __syncthreads();
  }

#pragma unroll
  for (int mi = 0; mi < FM; ++mi) {
    int mbase = row0 + wr * WM + mi * 16 + lhi * 4;
#pragma unroll
    for (int ni = 0; ni < FN; ++ni) {
      int n = col0 + wc * WN + ni * 16 + l15;
      if constexpr (OUT == 1) {
        float b = bias[n];
        ushort* C = (ushort*)Cout;
#pragma unroll
        for (int j = 0; j < 4; ++j) C[(size_t)(mbase + j) * N + n] = f2bf(fmaxf(acc[mi][ni][j] + b, 0.f));
      } else if constexpr (OUT == 3) {
        float* C = (float*)Cout + (size_t)blockIdx.z * M * N;
#pragma unroll
        for (int j = 0; j < 4; ++j) C[(size_t)(mbase + j) * N + n] = acc[mi][ni][j];
      } else {
        int sect = n >> 9, nn = n & 511;
        float b = sect == 0 ? bias[nn] : (sect == 1 ? bias2[nn] : bias3[nn]);
        int bb = mbase >> 10;
        int s = mbase & 1023;
        if (sect == 0) {
#pragma unroll
          for (int j = 0; j < 4; ++j) q_out[(size_t)(mbase + j) * 512 + nn] = f2bf(acc[mi][ni][j] + b);
        } else if (sect == 1) {
#pragma unroll
          for (int j = 0; j < 4; ++j)
            k_out[((size_t)bb * EXTA + 128 + s + j) * 512 + nn] = f2bf(acc[mi][ni][j] + b);
        } else {
          ushort4 pk;
          pk.x = f2bf(acc[mi][ni][0] + b);
          pk.y = f2bf(acc[mi][ni][1] + b);
          pk.z = f2bf(acc[mi][ni][2] + b);
          pk.w = f2bf(acc[mi][ni][3] + b);
          *(ushort4*)&v_out[((size_t)bb * 512 + nn) * EXTA + 128 + s] = pk;
        }
      }
    }
  }
}

// ---------------- banded MFMA attention + fused residual LayerNorm1 ----------------
// block = 16-row q-tile, 8 waves, covers full 512 cols -> in-block LN
__global__ __launch_bounds__(512) void attn_ln1(const ushort* __restrict__ qb,
                                                const ushort* __restrict__ kb,
                                                const ushort* __restrict__ vt,
                                                const float* __restrict__ x_pe,
                                                const float* __restrict__ ln1w,
                                                const float* __restrict__ ln1b,
                                                float* __restrict__ x1,
                                                ushort* __restrict__ x1bf) {
  __shared__ float e_s[16][292];
  __shared__ ushort p_s[16][296];
  __shared__ float inv_s[16];
  __shared__ float redS[8][16];
  __shared__ float redQ[8][16];
  __shared__ float mu_s[16], rs_s[16];
  const int tid = threadIdx.x;
  const int lane = tid & 63;
  const int w = tid >> 6;          // 0..7
  const int l15 = lane & 15, lhi = lane >> 4;
  const int tile = blockIdx.x;     // 0..127
  const int b = tile >> 6;
  const int s0 = (tile & 63) * 16;
  const int base0 = b * 1024 + s0;

  const ushort* qrow = qb + (size_t)(base0 + l15) * 512 + lhi * 8;
  bf16x8 qf[16];
#pragma unroll
  for (int ks = 0; ks < 16; ++ks) qf[ks] = *(const bf16x8*)(qrow + ks * 32);

  const float scale = 0.044194173824159216f;  // 1/sqrt(512)
  const ushort* kbase = kb + (size_t)b * EXTA * 512 + (size_t)(s0 + l15) * 512 + lhi * 8;

  // energy: wave w -> j-tiles {w, w+8, w+16}
  for (int jt = w; jt < 18; jt += 8) {
    f32x4 acc = {};
    const ushort* kp = kbase + (size_t)jt * 16 * 512;
#pragma unroll
    for (int ks = 0; ks < 16; ++ks) {
      bf16x8 kf = *(const bf16x8*)(kp + ks * 32);
      acc = __builtin_amdgcn_mfma_f32_16x16x32_bf16(qf[ks], kf, acc, 0, 0, 0);
    }
    int jc = jt * 16 + l15;
#pragma unroll
    for (int j = 0; j < 4; ++j) {
      int i = lhi * 4 + j;
      bool valid = (jc >= i) && (jc <= i + 256);
      e_s[i][jc] = valid ? acc[j] * scale : -1e30f;
    }
  }
  __syncthreads();

  // softmax: row r = tid>>5, 32 lanes per row over 288 cols
  {
    int r = tid >> 5, c0 = tid & 31;
    float m = -1e30f;
#pragma unroll
    for (int t = 0; t < 9; ++t) m = fmaxf(m, e_s[r][c0 + 32 * t]);
#pragma unroll
    for (int off = 1; off <= 16; off <<= 1) m = fmaxf(m, __shfl_xor(m, off));
    float s = 0.f;
#pragma unroll
    for (int t = 0; t < 9; ++t) {
      float p = __expf(e_s[r][c0 + 32 * t] - m);
      s += p;
      p_s[r][c0 + 32 * t] = f2bf(p);
    }
#pragma unroll
    for (int off = 1; off <= 16; off <<= 1) s += __shfl_xor(s, off);
    if (c0 == 0) inv_s[r] = 1.0f / s;
  }
  __syncthreads();

  // PV: wave w -> n-tiles w*4 .. w*4+3; keep results in regs for LN
  bf16x8 pf[9];
#pragma unroll
  for (int ks = 0; ks < 9; ++ks) pf[ks] = *(const bf16x8*)&p_s[l15][ks * 32 + lhi * 8];
  float inv[4];
#pragma unroll
  for (int j = 0; j < 4; ++j) inv[j] = inv_s[lhi * 4 + j];

  const ushort* vbase = vt + (size_t)b * 512 * EXTA + s0 + lhi * 8;
  float val[4][4];  // [ni][j]
#pragma unroll
  for (int ni = 0; ni < 4; ++ni) {
    int n = w * 64 + ni * 16 + l15;
    f32x4 acc = {};
    const ushort* vp = vbase + (size_t)n * EXTA;
#pragma unroll
    for (int ks = 0; ks < 9; ++ks) {
      bf16x8 vf = *(const bf16x8*)(vp + ks * 32);
      acc = __builtin_amdgcn_mfma_f32_16x16x32_bf16(pf[ks], vf, acc, 0, 0, 0);
    }
#pragma unroll
    for (int j = 0; j < 4; ++j) {
      int r = lhi * 4 + j;
      val[ni][j] = acc[j] * inv[j] + x_pe[(size_t)(base0 + r) * 512 + n];
    }
  }

  // LN1 stats: per-row sums across the block
  float S[4], Q[4];
#pragma unroll
  for (int j = 0; j < 4; ++j) {
    S[j] = 0.f; Q[j] = 0.f;
#pragma unroll
    for (int ni = 0; ni < 4; ++ni) { S[j] += val[ni][j]; Q[j] += val[ni][j] * val[ni][j]; }
  }
#pragma unroll
  for (int off = 1; off <= 8; off <<= 1) {
#pragma unroll
    for (int j = 0; j < 4; ++j) {
      S[j] += __shfl_xor(S[j], off);
      Q[j] += __shfl_xor(Q[j], off);
    }
  }
  if (l15 == 0) {
#pragma unroll
    for (int j = 0; j < 4; ++j) { redS[w][lhi * 4 + j] = S[j]; redQ[w][lhi * 4 + j] = Q[j]; }
  }
  __syncthreads();
  if (tid < 16) {
    float sS = 0.f, sQ = 0.f;
#pragma unroll
    for (int ww = 0; ww < 8; ++ww) { sS += redS[ww][tid]; sQ += redQ[ww][tid]; }
    float mu = sS * (1.0f / 512.0f);
    float var = sQ * (1.0f / 512.0f) - mu * mu;
    mu_s[tid] = mu;
    rs_s[tid] = rsqrtf(var + 1e-5f);
  }
  __syncthreads();

#pragma unroll
  for (int ni = 0; ni < 4; ++ni) {
    int n = w * 64 + ni * 16 + l15;
    float lw = ln1w[n], lb = ln1b[n];
#pragma unroll
    for (int j = 0; j < 4; ++j) {
      int r = lhi * 4 + j;
      float o = (val[ni][j] - mu_s[r]) * rs_s[r] * lw + lb;
      x1[(size_t)(base0 + r) * 512 + n] = o;
      x1bf[(size_t)(base0 + r) * 512 + n] = f2bf(o);
    }
  }
}

// ---------------- residual + LayerNorm (a [+ a2 + ab] + rsd) ----------------
__device__ inline float wave_reduce_sum(float v) {
#pragma unroll
  for (int off = 32; off >= 1; off >>= 1) v += __shfl_xor(v, off);
  return v;
}

__global__ __launch_bounds__(256) void ln_kernel(const float* __restrict__ a,
                                                 const float* __restrict__ a2,
                                                 const float* __restrict__ ab,
                                                 const float* __restrict__ rsd,
                                                 const float* __restrict__ w,
                                                 const float* __restrict__ bias,
                                                 float* __restrict__ out) {
  const int row = blockIdx.x;
  const int tid = threadIdx.x;
  __shared__ float red[8];
  const int e0 = tid * 2;
  const size_t base = (size_t)row * E_DIM + e0;
  float2 av = *(const float2*)(a + base);
  float2 rv = *(const float2*)(rsd + base);
  float x0 = av.x + rv.x, x1 = av.y + rv.y;
  {
    float2 v2 = *(const float2*)(a2 + base);
    x0 += v2.x; x1 += v2.y;
  }
  {
    float2 bb = *(const float2*)(ab + e0);
    x0 += bb.x; x1 += bb.y;
  }

  float sm = wave_reduce_sum(x0 + x1);
  if ((tid & 63) == 0) red[tid >> 6] = sm;
  __syncthreads();
  float mu = (red[0] + red[1] + red[2] + red[3]) * (1.0f / 512.0f);
  float d0 = x0 - mu, d1 = x1 - mu;
  float vs = wave_reduce_sum(d0 * d0 + d1 * d1);
  if ((tid & 63) == 0) red[4 + (tid >> 6)] = vs;
  __syncthreads();
  float var = (red[4] + red[5] + red[6] + red[7]) * (1.0f / 512.0f);
  float inv = rsqrtf(var + 1e-5f);
  float2 wv = *(const float2*)(w + e0);
  float2 bi = *(const float2*)(bias + e0);
  float o0 = d0 * inv * wv.x + bi.x;
  float o1 = d1 * inv * wv.y + bi.y;
  *(float2*)(out + base) = make_float2(o0, o1);
}

// ---------------- launch ----------------
extern "C" void kernel_launch(void* const* d_in, const int* in_sizes, int n_in,
                              void* d_out, int out_size, void* d_ws, size_t ws_size,
                              hipStream_t stream) {
  const float* x    = (const float*)d_in[0];
  const float* wq   = (const float*)d_in[1];
  const float* bq   = (const float*)d_in[2];
  const float* wk   = (const float*)d_in[3];
  const float* bk   = (const float*)d_in[4];
  const float* wv   = (const float*)d_in[5];
  const float* bv   = (const float*)d_in[6];
  const float* w1   = (const float*)d_in[7];
  const float* b1   = (const float*)d_in[8];
  const float* w2   = (const float*)d_in[9];
  const float* b2   = (const float*)d_in[10];
  const float* ln1w = (const float*)d_in[11];
  const float* ln1b = (const float*)d_in[12];
  const float* ln2w = (const float*)d_in[13];
  const float* ln2b = (const float*)d_in[14];

  char* W = (char*)d_ws;
  float*  x_pe   = (float*)(W);                      // 4MB  @0
  ushort* xpebf  = (ushort*)(W + (4u  << 20));       // 2MB  @4
  ushort* wqkvT  = (ushort*)(W + (6u  << 20));       // 1.5MB@6
  ushort* w1T    = (ushort*)(W + (8u  << 20));       // 2MB  @8
  ushort* w2T    = (ushort*)(W + (10u << 20));       // 2MB  @10
  ushort* q_bf   = (ushort*)(W + (12u << 20));       // 2MB  @12
  ushort* k_bf   = (ushort*)(W + (14u << 20));       // 2.6MB@14
  ushort* v_t    = (ushort*)(W + (17u << 20));       // 2.6MB@17
  float*  x1     = (float*)(W + (20u << 20));        // 4MB  @20
  ushort* x1bf   = (ushort*)(W + (24u << 20));       // 2MB  @24
  ushort* ff1_bf = (ushort*)(W + (26u << 20));       // 8MB  @26
  float*  ff2    = (float*)(W + (34u << 20));        // 2x4MB@34 (split-K partials)

  prep_kernel<<<9088, 256, 0, stream>>>(x, bk, bv, wq, wk, wv, w1, w2,
                                        x_pe, xpebf, k_bf, v_t, wqkvT, w1T, w2T);

  // QKV fused: M=2048, N=1536, K=512
  mfma_gemm<64, 128, 32, 64, 2><<<dim3(12, 32), 256, 0, stream>>>(
      xpebf, wqkvT, bq, bk, bv, nullptr, q_bf, k_bf, v_t, BS_ROWS, 1536, 512, 512);

  attn_ln1<<<128, 512, 0, stream>>>(q_bf, k_bf, v_t, x_pe, ln1w, ln1b, x1, x1bf);

  // FFN1: M=2048, N=2048, K=512, relu, bf16 out
  mfma_gemm<64, 128, 32, 64, 1><<<dim3(16, 32), 256, 0, stream>>>(
      x1bf, w1T, b1, nullptr, nullptr, ff1_bf, nullptr, nullptr, nullptr, BS_ROWS, H_DIM, 512, 512);

  // FFN2: M=2048, N=512, K=2048 split-K x2 -> fp32 partials
  mfma_gemm<64, 64, 32, 32, 3><<<dim3(8, 32, 2), 256, 0, stream>>>(
      ff1_bf, w2T, nullptr, nullptr, nullptr, ff2, nullptr, nullptr, nullptr, BS_ROWS, E_DIM, 1024, 2048);

  // LN2: (ff2a + ff2b + b2) + x1 residual
  ln_kernel<<<BS_ROWS, 256, 0, stream>>>(ff2, ff2 + (size_t)BS_ROWS * E_DIM, b2, x1,
                                         ln2w, ln2b, (float*)d_out);
}